// Round 1
// baseline (5387.806 us; speedup 1.0000x reference)
//
#include <hip/hip_runtime.h>

// ARMA GNN (T=1,K=1) x2 layers on MI355X.
// Decomposition per layer:
//   p[i]   = (h[i] @ W) * dinv[i]              (proj_kernel, per node)
//   agg[c] += sum_{e: col=c} p[row_e]          (scatter_kernel, per edge, atomics)
//   out[i] = relu(dinv[i]*agg[i] + h[i]@V + b) (finish_kernel, per node)
// dinv folded at both endpoints => no per-edge norm multiply.

__global__ void deg_kernel(const int* __restrict__ col, float* __restrict__ deg, int E) {
    int i = blockIdx.x * blockDim.x + threadIdx.x;
    if (i < E) atomicAdd(deg + col[i], 1.0f);
}

__global__ void dinv_kernel(float* __restrict__ deg, int n) {
    int i = blockIdx.x * blockDim.x + threadIdx.x;
    if (i < n) {
        float d = deg[i];
        deg[i] = (d > 0.0f) ? rsqrtf(d) : 0.0f;
    }
}

template <int FI>
__global__ void proj_kernel(const float* __restrict__ hin, const float* __restrict__ W,
                            const float* __restrict__ dinv, float* __restrict__ p, int n) {
    __shared__ float sW[FI * 16];
    for (int t = threadIdx.x; t < FI * 16; t += blockDim.x) sW[t] = W[t];
    __syncthreads();
    int i = blockIdx.x * blockDim.x + threadIdx.x;
    if (i >= n) return;
    float hi[FI];
    const float4* hr = (const float4*)(hin + (size_t)i * FI);
#pragma unroll
    for (int k = 0; k < FI / 4; k++) {
        float4 v = hr[k];
        hi[4 * k] = v.x; hi[4 * k + 1] = v.y; hi[4 * k + 2] = v.z; hi[4 * k + 3] = v.w;
    }
    float di = dinv[i];
    float out[16];
#pragma unroll
    for (int f = 0; f < 16; f++) {
        float s = 0.0f;
#pragma unroll
        for (int k = 0; k < FI; k++) s += hi[k] * sW[k * 16 + f];
        out[f] = s * di;
    }
    float4* pr = (float4*)(p + (size_t)i * 16);
#pragma unroll
    for (int q = 0; q < 4; q++)
        pr[q] = make_float4(out[4 * q], out[4 * q + 1], out[4 * q + 2], out[4 * q + 3]);
}

__global__ void scatter_kernel(const int* __restrict__ row, const int* __restrict__ col,
                               const float* __restrict__ p, float* __restrict__ agg, int E) {
    int e = blockIdx.x * blockDim.x + threadIdx.x;
    if (e >= E) return;
    int r = row[e], c = col[e];
    const float4* pr = (const float4*)(p + (size_t)r * 16);
    float* ag = agg + (size_t)c * 16;
#pragma unroll
    for (int q = 0; q < 4; q++) {
        float4 v = pr[q];
        atomicAdd(ag + 4 * q + 0, v.x);
        atomicAdd(ag + 4 * q + 1, v.y);
        atomicAdd(ag + 4 * q + 2, v.z);
        atomicAdd(ag + 4 * q + 3, v.w);
    }
}

// NOTE: hin/out may alias (layer 2 reads h from d_out and overwrites it) -> no
// __restrict__ on those two. Each thread reads its full row before writing it.
template <int FI>
__global__ void finish_kernel(const float* __restrict__ agg, const float* hin,
                              const float* __restrict__ V, const float* __restrict__ b,
                              const float* __restrict__ dinv, float* out, int n) {
    __shared__ float sV[FI * 16];
    __shared__ float sb[16];
    for (int t = threadIdx.x; t < FI * 16; t += blockDim.x) sV[t] = V[t];
    if (threadIdx.x < 16) sb[threadIdx.x] = b[threadIdx.x];
    __syncthreads();
    int i = blockIdx.x * blockDim.x + threadIdx.x;
    if (i >= n) return;
    float hi[FI];
    const float4* hr = (const float4*)(hin + (size_t)i * FI);
#pragma unroll
    for (int k = 0; k < FI / 4; k++) {
        float4 v = hr[k];
        hi[4 * k] = v.x; hi[4 * k + 1] = v.y; hi[4 * k + 2] = v.z; hi[4 * k + 3] = v.w;
    }
    float ag[16];
    const float4* ar = (const float4*)(agg + (size_t)i * 16);
#pragma unroll
    for (int k = 0; k < 4; k++) {
        float4 v = ar[k];
        ag[4 * k] = v.x; ag[4 * k + 1] = v.y; ag[4 * k + 2] = v.z; ag[4 * k + 3] = v.w;
    }
    float di = dinv[i];
    float res[16];
#pragma unroll
    for (int f = 0; f < 16; f++) {
        float s = sb[f] + di * ag[f];
#pragma unroll
        for (int k = 0; k < FI; k++) s += hi[k] * sV[k * 16 + f];
        res[f] = s > 0.0f ? s : 0.0f;
    }
    float4* orow = (float4*)(out + (size_t)i * 16);
#pragma unroll
    for (int q = 0; q < 4; q++)
        orow[q] = make_float4(res[4 * q], res[4 * q + 1], res[4 * q + 2], res[4 * q + 3]);
}

extern "C" void kernel_launch(void* const* d_in, const int* in_sizes, int n_in,
                              void* d_out, int out_size, void* d_ws, size_t ws_size,
                              hipStream_t stream) {
    const float* x  = (const float*)d_in[0];
    const int*   ei = (const int*)d_in[1];
    const float* W1 = (const float*)d_in[2];
    const float* V1 = (const float*)d_in[3];
    const float* b1 = (const float*)d_in[4];
    const float* W2 = (const float*)d_in[5];
    const float* V2 = (const float*)d_in[6];
    const float* b2 = (const float*)d_in[7];

    const int n = in_sizes[0] / 8;       // 100000 nodes
    const int E = in_sizes[1] / 2;       // 3200000 edges
    const int* row = ei;                 // edge_index[0]
    const int* col = ei + E;             // edge_index[1]

    char* ws = (char*)d_ws;
    size_t o_dinv = 0;
    size_t o_p    = o_dinv + ((size_t)n * 4 + 255) / 256 * 256;
    size_t o_agg  = o_p + ((size_t)n * 16 * 4 + 255) / 256 * 256;
    float* dinv = (float*)(ws + o_dinv);
    float* p    = (float*)(ws + o_p);
    float* agg  = (float*)(ws + o_agg);
    float* out  = (float*)d_out;

    const int bs = 256;
    const int gbE = (E + bs - 1) / bs;
    const int gbN = (n + bs - 1) / bs;

    hipMemsetAsync(dinv, 0, (size_t)n * 4, stream);
    hipMemsetAsync(agg, 0, (size_t)n * 16 * 4, stream);

    deg_kernel<<<gbE, bs, 0, stream>>>(col, dinv, E);
    dinv_kernel<<<gbN, bs, 0, stream>>>(dinv, n);

    // Layer 1 (FI=8): h -> d_out
    proj_kernel<8><<<gbN, bs, 0, stream>>>(x, W1, dinv, p, n);
    scatter_kernel<<<gbE, bs, 0, stream>>>(row, col, p, agg, E);
    finish_kernel<8><<<gbN, bs, 0, stream>>>(agg, x, V1, b1, dinv, out, n);

    // Layer 2 (FI=16): reads h from d_out, overwrites d_out with final result
    hipMemsetAsync(agg, 0, (size_t)n * 16 * 4, stream);
    proj_kernel<16><<<gbN, bs, 0, stream>>>(out, W2, dinv, p, n);
    scatter_kernel<<<gbE, bs, 0, stream>>>(row, col, p, agg, E);
    finish_kernel<16><<<gbN, bs, 0, stream>>>(agg, out, V2, b2, dinv, out, n);
}

// Round 2
// 792.635 us; speedup vs baseline: 6.7973x; 6.7973x over previous
//
#include <hip/hip_runtime.h>

// ARMA GNN (T=1,K=1) x2 layers on MI355X — CSR-gather formulation.
//
// Per layer:
//   p[i]   = (h[i] @ W) * dinv[i]                     (proj_kernel)
//   out[c] = relu(dinv[c] * Sum_{e in CSR[c]} p[srt_row[e]] + h[c]@V + b)
//                                                     (gather_finish_kernel, NO fp32 atomics)
// CSR (counting sort of edges by col) built once, shared by both layers:
//   count -> scan(ptr, fill, dinv) -> reorder(srt_row)

#define SCAN_T 1024

__global__ void count_kernel(const int* __restrict__ col, int* __restrict__ cnt, int E) {
    int i = blockIdx.x * blockDim.x + threadIdx.x;
    if (i < E) atomicAdd(cnt + col[i], 1);
}

// Single-block exclusive scan: cnt[0..n) -> ptr[0..n], fill copy, and dinv = rsqrt(deg).
__global__ void scan_kernel(const int* __restrict__ cnt, int* __restrict__ ptr,
                            int* __restrict__ fill, float* __restrict__ dinv,
                            int n, int E) {
    __shared__ int sums[SCAN_T];
    int t = threadIdx.x;
    int chunk = (n + SCAN_T - 1) / SCAN_T;
    int lo = t * chunk;
    int hi = lo + chunk; if (hi > n) hi = n;
    int s = 0;
    for (int i = lo; i < hi; i++) s += cnt[i];
    sums[t] = s;
    __syncthreads();
    for (int off = 1; off < SCAN_T; off <<= 1) {
        int v = 0;
        if (t >= off) v = sums[t - off];
        __syncthreads();
        if (t >= off) sums[t] += v;
        __syncthreads();
    }
    int run = sums[t] - s;  // exclusive prefix of this thread's chunk
    for (int i = lo; i < hi; i++) {
        int c = cnt[i];
        ptr[i] = run;
        fill[i] = run;
        dinv[i] = (c > 0) ? rsqrtf((float)c) : 0.0f;
        run += c;
    }
    if (t == 0) ptr[n] = E;
}

__global__ void reorder_kernel(const int* __restrict__ row, const int* __restrict__ col,
                               int* __restrict__ fill, int* __restrict__ srt, int E) {
    int e = blockIdx.x * blockDim.x + threadIdx.x;
    if (e < E) {
        int pos = atomicAdd(fill + col[e], 1);
        srt[pos] = row[e];
    }
}

template <int FI>
__global__ void proj_kernel(const float* __restrict__ hin, const float* __restrict__ W,
                            const float* __restrict__ dinv, float* __restrict__ p, int n) {
    __shared__ float sW[FI * 16];
    for (int t = threadIdx.x; t < FI * 16; t += blockDim.x) sW[t] = W[t];
    __syncthreads();
    int i = blockIdx.x * blockDim.x + threadIdx.x;
    if (i >= n) return;
    float hi[FI];
    const float4* hr = (const float4*)(hin + (size_t)i * FI);
#pragma unroll
    for (int k = 0; k < FI / 4; k++) {
        float4 v = hr[k];
        hi[4 * k] = v.x; hi[4 * k + 1] = v.y; hi[4 * k + 2] = v.z; hi[4 * k + 3] = v.w;
    }
    float di = dinv[i];
    float out[16];
#pragma unroll
    for (int f = 0; f < 16; f++) {
        float s = 0.0f;
#pragma unroll
        for (int k = 0; k < FI; k++) s += hi[k] * sW[k * 16 + f];
        out[f] = s * di;
    }
    float4* pr = (float4*)(p + (size_t)i * 16);
#pragma unroll
    for (int q = 0; q < 4; q++)
        pr[q] = make_float4(out[4 * q], out[4 * q + 1], out[4 * q + 2], out[4 * q + 3]);
}

// 16 lanes per node; lane f owns feature f. Gathers are one 64B line per edge.
// hin/out may alias (layer 2): each group reads only its OWN h row, then writes it.
template <int FI>
__global__ void gather_finish_kernel(const int* __restrict__ ptr, const int* __restrict__ srt,
                                     const float* __restrict__ p, const float* hin,
                                     const float* __restrict__ V, const float* __restrict__ b,
                                     const float* __restrict__ dinv, float* out, int n) {
    __shared__ float sV[FI * 16];
    __shared__ float sb[16];
    for (int t = threadIdx.x; t < FI * 16; t += blockDim.x) sV[t] = V[t];
    if (threadIdx.x < 16) sb[threadIdx.x] = b[threadIdx.x];
    __syncthreads();
    int g = blockIdx.x * (blockDim.x >> 4) + (threadIdx.x >> 4);
    int f = threadIdx.x & 15;
    if (g >= n) return;
    int s0 = ptr[g], s1 = ptr[g + 1];
    float acc = 0.0f;
    int e = s0;
    // unroll-by-4 for memory-level parallelism on the dependent srt->p chain
    for (; e + 4 <= s1; e += 4) {
        int r0 = srt[e], r1 = srt[e + 1], r2 = srt[e + 2], r3 = srt[e + 3];
        float a0 = p[(size_t)r0 * 16 + f];
        float a1 = p[(size_t)r1 * 16 + f];
        float a2 = p[(size_t)r2 * 16 + f];
        float a3 = p[(size_t)r3 * 16 + f];
        acc += a0 + a1 + a2 + a3;
    }
    for (; e < s1; e++) acc += p[(size_t)srt[e] * 16 + f];
    // fused finish: h@V + b + dinv*agg, relu
    float hv = 0.0f;
    const float* hrow = hin + (size_t)g * FI;
#pragma unroll
    for (int k = 0; k < FI; k++) hv += hrow[k] * sV[k * 16 + f];
    float res = sb[f] + dinv[g] * acc + hv;
    out[(size_t)g * 16 + f] = res > 0.0f ? res : 0.0f;
}

extern "C" void kernel_launch(void* const* d_in, const int* in_sizes, int n_in,
                              void* d_out, int out_size, void* d_ws, size_t ws_size,
                              hipStream_t stream) {
    const float* x  = (const float*)d_in[0];
    const int*   ei = (const int*)d_in[1];
    const float* W1 = (const float*)d_in[2];
    const float* V1 = (const float*)d_in[3];
    const float* b1 = (const float*)d_in[4];
    const float* W2 = (const float*)d_in[5];
    const float* V2 = (const float*)d_in[6];
    const float* b2 = (const float*)d_in[7];

    const int n = in_sizes[0] / 8;       // 100000 nodes
    const int E = in_sizes[1] / 2;       // 3200000 edges
    const int* row = ei;                 // edge_index[0]
    const int* col = ei + E;             // edge_index[1]

    auto align = [](size_t v) { return (v + 255) / 256 * 256; };
    char* ws = (char*)d_ws;
    size_t off = 0;
    float* dinv = (float*)(ws + off); off += align((size_t)n * 4);
    int*   cnt  = (int*)(ws + off);   off += align((size_t)n * 4);
    int*   ptr  = (int*)(ws + off);   off += align((size_t)(n + 1) * 4);
    int*   fill = (int*)(ws + off);   off += align((size_t)n * 4);
    int*   srt  = (int*)(ws + off);   off += align((size_t)E * 4);
    float* p    = (float*)(ws + off); off += align((size_t)n * 16 * 4);
    float* out  = (float*)d_out;
    // total ws use ~20.8 MB

    const int bs = 256;
    const int gbE = (E + bs - 1) / bs;
    const int gbN = (n + bs - 1) / bs;
    const int gbG = (n * 16 + bs - 1) / bs;  // gather: 16 lanes per node

    hipMemsetAsync(cnt, 0, (size_t)n * 4, stream);

    // CSR build (shared by both layers)
    count_kernel<<<gbE, bs, 0, stream>>>(col, cnt, E);
    scan_kernel<<<1, SCAN_T, 0, stream>>>(cnt, ptr, fill, dinv, n, E);
    reorder_kernel<<<gbE, bs, 0, stream>>>(row, col, fill, srt, E);

    // Layer 1 (FI=8): x -> d_out
    proj_kernel<8><<<gbN, bs, 0, stream>>>(x, W1, dinv, p, n);
    gather_finish_kernel<8><<<gbG, bs, 0, stream>>>(ptr, srt, p, x, V1, b1, dinv, out, n);

    // Layer 2 (FI=16): d_out -> d_out
    proj_kernel<16><<<gbN, bs, 0, stream>>>(out, W2, dinv, p, n);
    gather_finish_kernel<16><<<gbG, bs, 0, stream>>>(ptr, srt, p, out, V2, b2, dinv, out, n);
}

// Round 3
// 454.700 us; speedup vs baseline: 11.8491x; 1.7432x over previous
//
#include <hip/hip_runtime.h>

// ARMA GNN (T=1,K=1) x2 layers on MI355X — CSR-gather formulation.
//
// Per layer:
//   p[i]   = (h[i] @ W) * dinv[i]                     (proj_kernel)
//   out[c] = relu(dinv[c] * Sum_{e in CSR[c]} p[srt_row[e]] + h[c]@V + b)
//                                                     (gather_finish_kernel, NO fp32 atomics)
// CSR (counting sort of edges by col) built once, shared by both layers:
//   count -> hierarchical scan(ptr, fill, dinv) -> reorder in 8 col-range passes
// Range passes keep the srt write window at 1.6 MB (L2-resident) to kill the
// 15x partial-line write amplification seen in round 2 (194 MB -> ~13 MB).

#define NPASS 8

__global__ void count_kernel(const int* __restrict__ col, int* __restrict__ cnt, int E) {
    int i = blockIdx.x * blockDim.x + threadIdx.x;
    if (i < E) atomicAdd(cnt + __builtin_nontemporal_load(col + i), 1);
}

// ---- hierarchical exclusive scan over cnt[0..n) -> ptr/fill/dinv ----
// A: block b reduces cnt[b*1024 .. b*1024+1023] -> bsum[b]
__global__ void scan_partial_kernel(const int* __restrict__ cnt, int* __restrict__ bsum, int n) {
    __shared__ int red[256];
    int b = blockIdx.x, t = threadIdx.x;
    int base = b * 1024;
    int s = 0;
    for (int i = t; i < 1024; i += 256) {
        int idx = base + i;
        if (idx < n) s += cnt[idx];
    }
    red[t] = s;
    __syncthreads();
    for (int o = 128; o > 0; o >>= 1) {
        if (t < o) red[t] += red[t + o];
        __syncthreads();
    }
    if (t == 0) bsum[b] = red[0];
}

// B: tiny serial exclusive scan of bsum[nb] (nb ~ 98)
__global__ void scan_base_kernel(int* __restrict__ bsum, int nb) {
    if (threadIdx.x == 0) {
        int run = 0;
        for (int i = 0; i < nb; i++) { int v = bsum[i]; bsum[i] = run; run += v; }
    }
}

// C: block b: LDS scan of its 1024 cols, + bbase[b]; writes ptr, fill, dinv.
__global__ void scan_final_kernel(const int* __restrict__ cnt, const int* __restrict__ bbase,
                                  int* __restrict__ ptr, int* __restrict__ fill,
                                  float* __restrict__ dinv, int n, int E) {
    __shared__ int tsum[256];
    int b = blockIdx.x, t = threadIdx.x;
    int base = b * 1024 + t * 4;
    int c[4];
#pragma unroll
    for (int k = 0; k < 4; k++) c[k] = (base + k < n) ? cnt[base + k] : 0;
    int s = c[0] + c[1] + c[2] + c[3];
    tsum[t] = s;
    __syncthreads();
    for (int off = 1; off < 256; off <<= 1) {
        int v = 0;
        if (t >= off) v = tsum[t - off];
        __syncthreads();
        if (t >= off) tsum[t] += v;
        __syncthreads();
    }
    int run = bbase[b] + tsum[t] - s;  // exclusive prefix for this thread's 4 cols
#pragma unroll
    for (int k = 0; k < 4; k++) {
        int i = base + k;
        if (i < n) {
            ptr[i] = run;
            fill[i] = run;
            dinv[i] = (c[k] > 0) ? rsqrtf((float)c[k]) : 0.0f;
            run += c[k];
        }
    }
    if (b == 0 && t == 0) ptr[n] = E;
}

// One pass per col range [lo,hi): srt write window stays L2-resident.
__global__ void reorder_range_kernel(const int* __restrict__ row, const int* __restrict__ col,
                                     int* __restrict__ fill, int* __restrict__ srt,
                                     int E, int lo, int hi) {
    int e = blockIdx.x * blockDim.x + threadIdx.x;
    if (e >= E) return;
    int c = __builtin_nontemporal_load(col + e);
    if ((unsigned)(c - lo) >= (unsigned)(hi - lo)) return;
    int r = __builtin_nontemporal_load(row + e);
    int pos = atomicAdd(fill + c, 1);
    srt[pos] = r;
}

template <int FI>
__global__ void proj_kernel(const float* __restrict__ hin, const float* __restrict__ W,
                            const float* __restrict__ dinv, float* __restrict__ p, int n) {
    __shared__ float sW[FI * 16];
    for (int t = threadIdx.x; t < FI * 16; t += blockDim.x) sW[t] = W[t];
    __syncthreads();
    int i = blockIdx.x * blockDim.x + threadIdx.x;
    if (i >= n) return;
    float hi[FI];
    const float4* hr = (const float4*)(hin + (size_t)i * FI);
#pragma unroll
    for (int k = 0; k < FI / 4; k++) {
        float4 v = hr[k];
        hi[4 * k] = v.x; hi[4 * k + 1] = v.y; hi[4 * k + 2] = v.z; hi[4 * k + 3] = v.w;
    }
    float di = dinv[i];
    float out[16];
#pragma unroll
    for (int f = 0; f < 16; f++) {
        float s = 0.0f;
#pragma unroll
        for (int k = 0; k < FI; k++) s += hi[k] * sW[k * 16 + f];
        out[f] = s * di;
    }
    float4* pr = (float4*)(p + (size_t)i * 16);
#pragma unroll
    for (int q = 0; q < 4; q++)
        pr[q] = make_float4(out[4 * q], out[4 * q + 1], out[4 * q + 2], out[4 * q + 3]);
}

// 16 lanes per node; lane f owns feature f. Gathers are one 64B line per edge.
// hin/out may alias (layer 2): each group reads only its OWN h row, then writes it.
template <int FI>
__global__ void gather_finish_kernel(const int* __restrict__ ptr, const int* __restrict__ srt,
                                     const float* __restrict__ p, const float* hin,
                                     const float* __restrict__ V, const float* __restrict__ b,
                                     const float* __restrict__ dinv, float* out, int n) {
    __shared__ float sV[FI * 16];
    __shared__ float sb[16];
    for (int t = threadIdx.x; t < FI * 16; t += blockDim.x) sV[t] = V[t];
    if (threadIdx.x < 16) sb[threadIdx.x] = b[threadIdx.x];
    __syncthreads();
    int g = blockIdx.x * (blockDim.x >> 4) + (threadIdx.x >> 4);
    int f = threadIdx.x & 15;
    if (g >= n) return;
    int s0 = ptr[g], s1 = ptr[g + 1];
    float acc = 0.0f;
    int e = s0;
    // unroll-by-8 for memory-level parallelism on the dependent srt->p chain
    for (; e + 8 <= s1; e += 8) {
        int r[8];
#pragma unroll
        for (int q = 0; q < 8; q++) r[q] = srt[e + q];
        float a[8];
#pragma unroll
        for (int q = 0; q < 8; q++) a[q] = p[(size_t)r[q] * 16 + f];
        acc += ((a[0] + a[1]) + (a[2] + a[3])) + ((a[4] + a[5]) + (a[6] + a[7]));
    }
    for (; e < s1; e++) acc += p[(size_t)srt[e] * 16 + f];
    // fused finish: h@V + b + dinv*agg, relu
    float hv = 0.0f;
    const float* hrow = hin + (size_t)g * FI;
#pragma unroll
    for (int k = 0; k < FI; k++) hv += hrow[k] * sV[k * 16 + f];
    float res = sb[f] + dinv[g] * acc + hv;
    out[(size_t)g * 16 + f] = res > 0.0f ? res : 0.0f;
}

extern "C" void kernel_launch(void* const* d_in, const int* in_sizes, int n_in,
                              void* d_out, int out_size, void* d_ws, size_t ws_size,
                              hipStream_t stream) {
    const float* x  = (const float*)d_in[0];
    const int*   ei = (const int*)d_in[1];
    const float* W1 = (const float*)d_in[2];
    const float* V1 = (const float*)d_in[3];
    const float* b1 = (const float*)d_in[4];
    const float* W2 = (const float*)d_in[5];
    const float* V2 = (const float*)d_in[6];
    const float* b2 = (const float*)d_in[7];

    const int n = in_sizes[0] / 8;       // 100000 nodes
    const int E = in_sizes[1] / 2;       // 3200000 edges
    const int* row = ei;                 // edge_index[0]
    const int* col = ei + E;             // edge_index[1]

    auto align = [](size_t v) { return (v + 255) / 256 * 256; };
    char* ws = (char*)d_ws;
    size_t off = 0;
    float* dinv = (float*)(ws + off); off += align((size_t)n * 4);
    int*   cnt  = (int*)(ws + off);   off += align((size_t)n * 4);
    int*   ptr  = (int*)(ws + off);   off += align((size_t)(n + 1) * 4);
    int*   fill = (int*)(ws + off);   off += align((size_t)n * 4);
    int*   bsum = (int*)(ws + off);   off += align((size_t)1024 * 4);
    int*   srt  = (int*)(ws + off);   off += align((size_t)E * 4);
    float* p    = (float*)(ws + off); off += align((size_t)n * 16 * 4);
    float* out  = (float*)d_out;
    // total ws use ~21 MB

    const int bs = 256;
    const int gbE = (E + bs - 1) / bs;
    const int gbN = (n + bs - 1) / bs;
    const int gbG = (n * 16 + bs - 1) / bs;  // gather: 16 lanes per node
    const int nb  = (n + 1023) / 1024;       // scan blocks

    hipMemsetAsync(cnt, 0, (size_t)n * 4, stream);

    // CSR build (shared by both layers)
    count_kernel<<<gbE, bs, 0, stream>>>(col, cnt, E);
    scan_partial_kernel<<<nb, 256, 0, stream>>>(cnt, bsum, n);
    scan_base_kernel<<<1, 64, 0, stream>>>(bsum, nb);
    scan_final_kernel<<<nb, 256, 0, stream>>>(cnt, bsum, ptr, fill, dinv, n, E);
    const int W = (n + NPASS - 1) / NPASS;
    for (int k = 0; k < NPASS; k++) {
        int lo = k * W;
        int hi = lo + W; if (hi > n) hi = n;
        reorder_range_kernel<<<gbE, bs, 0, stream>>>(row, col, fill, srt, E, lo, hi);
    }

    // Layer 1 (FI=8): x -> d_out
    proj_kernel<8><<<gbN, bs, 0, stream>>>(x, W1, dinv, p, n);
    gather_finish_kernel<8><<<gbG, bs, 0, stream>>>(ptr, srt, p, x, V1, b1, dinv, out, n);

    // Layer 2 (FI=16): d_out -> d_out
    proj_kernel<16><<<gbN, bs, 0, stream>>>(out, W2, dinv, p, n);
    gather_finish_kernel<16><<<gbG, bs, 0, stream>>>(ptr, srt, p, out, V2, b2, dinv, out, n);
}